// Round 6
// baseline (183.434 us; speedup 1.0000x reference)
//
#include <hip/hip_runtime.h>

#define IMG 512
#define HT_CS 52                  // shorts per Ht column (48 data + 4 pad = 104 B)
#define HT_COL (16 * HT_CS)       // one channel of one wave (16 cols)
#define HT_WV (5 * HT_COL)        // one wave's 5 channels (8320 shorts)

typedef short short8  __attribute__((ext_vector_type(8)));
typedef float floatx4 __attribute__((ext_vector_type(4)));
typedef int   intx2   __attribute__((ext_vector_type(2)));

// 1D Gaussian (sigma=1.5, K=11) — identical values to rounds 1-5.
__device__ static constexpr float W11F[11] = {
    0.00102838f, 0.00759876f, 0.03600077f, 0.10936069f, 0.21300554f,
    0.26601173f,
    0.21300554f, 0.10936069f, 0.03600077f, 0.00759876f, 0.00102838f};

// pack two fp32 -> two bf16 (round-half-up; finite positive values)
__device__ __forceinline__ unsigned pack2bf16(float a, float b) {
    const unsigned ua = __float_as_uint(a) + 0x8000u;
    const unsigned ub = __float_as_uint(b) + 0x8000u;
    return __builtin_amdgcn_perm(ub, ua, 0x07060302u);
}

__device__ __forceinline__ void ht_store(ushort* p, floatx4 c) {
    intx2 d;
    d.x = (int)pack2bf16(c[0], c[1]);
    d.y = (int)pack2bf16(c[2], c[3]);
    *(intx2*)p = d;
}

__device__ __forceinline__ short8 ht_load(const ushort* p) {
    union { intx2 d[2]; short8 s; } u;
    u.d[0] = *(const intx2*)p;
    u.d[1] = *(const intx2*)(p + 4);
    return u.s;
}

// 128-thread blocks (2 waves). Wave = 16 out-cols x 32 out-rows.
// H-pass stages 48 rows (3 row-tiles) -> V-pass emits 2 windows of 16 rows.
__global__ __launch_bounds__(128, 2) void ssim_mfma_kernel(
        const float* __restrict__ pred, const float* __restrict__ gt,
        float* __restrict__ partials)
{
    __shared__ ushort Ht[2 * HT_WV];   // 16,640 B
    __shared__ ushort wlut[16];
    __shared__ float wsum[2];

    const int tid  = threadIdx.x;
    const int wv   = tid >> 6;
    const int lane = tid & 63;
    const int n    = lane & 15;
    const int quad = lane >> 4;

    if (tid < 16) {
        const float w = (tid < 11) ? W11F[tid] : 0.f;
        wlut[tid] = (ushort)((__float_as_uint(w) + 0x8000u) >> 16);
    }
    __syncthreads();

    // band fragment: w[(quad*8+j) - n - 3]; B in H-pass, A in V-pass.
    short8 band;
#pragma unroll
    for (int j = 0; j < 8; ++j) {
        const int t = quad * 8 + j - n - 3;
        band[j] = (short)wlut[((unsigned)t < 11u) ? t : 15];
    }

    const int bx = blockIdx.x, by = blockIdx.y, plane = blockIdx.z;
    const long pb = (long)plane * (IMG * IMG);
    const int xs  = bx * 32 + wv * 16 - 8;   // 32-col K-window start
    const int y0  = by * 32;
    ushort* ht    = &Ht[wv * HT_WV];
    const bool cols_ok = (xs >= 0) && (xs + 32 <= IMG);

#define LOADRT(rt, pf, gf)                                                   \
    {                                                                        \
        const int ys  = y0 - 8 + (rt) * 16;                                  \
        const int row = ys + n;                                              \
        const int c0  = xs + quad * 8;                                       \
        if (cols_ok && ys >= 0 && ys + 16 <= IMG) {                          \
            const float* pr = pred + pb + (long)row * IMG + c0;              \
            const float* gr = gt   + pb + (long)row * IMG + c0;              \
            *(float4*)&pf[0] = *(const float4*)pr;                           \
            *(float4*)&pf[4] = *(const float4*)(pr + 4);                     \
            *(float4*)&gf[0] = *(const float4*)gr;                           \
            *(float4*)&gf[4] = *(const float4*)(gr + 4);                     \
        } else {                                                             \
            const bool rv = (unsigned)row < (unsigned)IMG;                   \
            const int rowc = rv ? row : 0;                                   \
            const float* pr = pred + pb + (long)rowc * IMG;                  \
            const float* gr = gt   + pb + (long)rowc * IMG;                  \
            _Pragma("unroll")                                                \
            for (int j = 0; j < 8; ++j) {                                    \
                const int cc = c0 + j;                                       \
                const bool ok = rv && ((unsigned)cc < (unsigned)IMG);        \
                const int ccc = ok ? cc : 0;                                 \
                const float pv = pr[ccc], gv = gr[ccc];                      \
                pf[j] = ok ? pv : 0.f;                                       \
                gf[j] = ok ? gv : 0.f;                                       \
            }                                                                \
        }                                                                    \
    }

#define COMPRT(rt, pf, gf)                                                   \
    {                                                                        \
        union { unsigned u[4]; short8 s; } ap, ag, app, agg, apg;            \
        _Pragma("unroll")                                                    \
        for (int h = 0; h < 4; ++h) {                                        \
            const float p0 = pf[2*h], p1 = pf[2*h+1];                        \
            const float g0 = gf[2*h], g1 = gf[2*h+1];                        \
            ap.u [h] = pack2bf16(p0, p1);                                    \
            ag.u [h] = pack2bf16(g0, g1);                                    \
            app.u[h] = pack2bf16(p0 * p0, p1 * p1);                          \
            agg.u[h] = pack2bf16(g0 * g0, g1 * g1);                          \
            apg.u[h] = pack2bf16(p0 * g0, p1 * g1);                          \
        }                                                                    \
        const floatx4 z = {0.f, 0.f, 0.f, 0.f};                              \
        const floatx4 cp  = __builtin_amdgcn_mfma_f32_16x16x32_bf16(ap.s,  band, z, 0, 0, 0); \
        const floatx4 cg  = __builtin_amdgcn_mfma_f32_16x16x32_bf16(ag.s,  band, z, 0, 0, 0); \
        const floatx4 cpp = __builtin_amdgcn_mfma_f32_16x16x32_bf16(app.s, band, z, 0, 0, 0); \
        const floatx4 cgg = __builtin_amdgcn_mfma_f32_16x16x32_bf16(agg.s, band, z, 0, 0, 0); \
        const floatx4 cpg = __builtin_amdgcn_mfma_f32_16x16x32_bf16(apg.s, band, z, 0, 0, 0); \
        const int wb = n * HT_CS + (rt) * 16 + quad * 4;                     \
        ht_store(&ht[0 * HT_COL + wb], cp);                                  \
        ht_store(&ht[1 * HT_COL + wb], cg);                                  \
        ht_store(&ht[2 * HT_COL + wb], cpp);                                 \
        ht_store(&ht[3 * HT_COL + wb], cgg);                                 \
        ht_store(&ht[4 * HT_COL + wb], cpg);                                 \
    }

    // ---- H pass, depth-2 software pipeline over 3 row-tiles ----
    {
        float pA[8], gA[8], pB[8], gB[8], pC[8], gC[8];
        LOADRT(0, pA, gA)
        LOADRT(1, pB, gB)
        COMPRT(0, pA, gA)
        LOADRT(2, pC, gC)
        COMPRT(1, pB, gB)
        COMPRT(2, pC, gC)
    }
    // wave reads back only its own Ht region; same-wave DS ordering suffices.

    // ---- V pass: 2 row-windows x 5 channels ----
    const float C1 = 1e-4f, C2 = 9e-4f;
    float lsum = 0.f;
#pragma unroll
    for (int wnd = 0; wnd < 2; ++wnd) {
        const int kb = n * HT_CS + wnd * 16 + quad * 8;
        const short8 bp  = ht_load(&ht[0 * HT_COL + kb]);
        const short8 bg  = ht_load(&ht[1 * HT_COL + kb]);
        const short8 bpp = ht_load(&ht[2 * HT_COL + kb]);
        const short8 bgg = ht_load(&ht[3 * HT_COL + kb]);
        const short8 bpg = ht_load(&ht[4 * HT_COL + kb]);

        const floatx4 z = {0.f, 0.f, 0.f, 0.f};
        const floatx4 mp  = __builtin_amdgcn_mfma_f32_16x16x32_bf16(band, bp,  z, 0, 0, 0);
        const floatx4 mg  = __builtin_amdgcn_mfma_f32_16x16x32_bf16(band, bg,  z, 0, 0, 0);
        const floatx4 mpp = __builtin_amdgcn_mfma_f32_16x16x32_bf16(band, bpp, z, 0, 0, 0);
        const floatx4 mgg = __builtin_amdgcn_mfma_f32_16x16x32_bf16(band, bgg, z, 0, 0, 0);
        const floatx4 mpg = __builtin_amdgcn_mfma_f32_16x16x32_bf16(band, bpg, z, 0, 0, 0);

#pragma unroll
        for (int r = 0; r < 4; ++r) {
            const float mu1 = mp[r], mu2 = mg[r];
            const float mu1sq = mu1 * mu1, mu2sq = mu2 * mu2, mu12 = mu1 * mu2;
            const float s1  = mpp[r] - mu1sq;
            const float s2  = mgg[r] - mu2sq;
            const float s12 = mpg[r] - mu12;
            const float num = (2.f * mu12 + C1) * (2.f * s12 + C2);
            const float den = (mu1sq + mu2sq + C1) * (s1 + s2 + C2);
            lsum += num * __builtin_amdgcn_rcpf(den);
        }
    }

    // ---- block reduction -> one partial per block ----
#pragma unroll
    for (int off = 32; off > 0; off >>= 1)
        lsum += __shfl_down(lsum, off);
    if (lane == 0) wsum[wv] = lsum;
    __syncthreads();
    if (tid == 0)
        partials[(plane * 16 + by) * 16 + bx] = wsum[0] + wsum[1];
}

__global__ __launch_bounds__(1024) void ssim_finalize(
        const float* __restrict__ partials, float* __restrict__ out,
        int nparts, double inv_n)
{
    __shared__ double ws[16];
    double s = 0.0;
    for (int i = threadIdx.x; i < nparts; i += 1024)
        s += (double)partials[i];
#pragma unroll
    for (int off = 32; off > 0; off >>= 1)
        s += __shfl_down(s, off);
    if ((threadIdx.x & 63) == 0) ws[threadIdx.x >> 6] = s;
    __syncthreads();
    if (threadIdx.x == 0) {
        double t = 0.0;
#pragma unroll
        for (int i = 0; i < 16; ++i) t += ws[i];
        out[0] = (float)(1.0 - t * inv_n);
    }
}

extern "C" void kernel_launch(void* const* d_in, const int* in_sizes, int n_in,
                              void* d_out, int out_size, void* d_ws, size_t ws_size,
                              hipStream_t stream)
{
    const float* pred = (const float*)d_in[0];
    const float* gt   = (const float*)d_in[1];
    float* out        = (float*)d_out;
    float* partials   = (float*)d_ws;          // 16*16*48 = 12288 floats

    const long n = (long)in_sizes[0];
    const int planes = (int)(n / (long)(IMG * IMG));   // B*C = 48

    dim3 grid(16, 16, planes);                 // 32-col x 32-row tiles
    ssim_mfma_kernel<<<grid, 128, 0, stream>>>(pred, gt, partials);
    ssim_finalize<<<1, 1024, 0, stream>>>(partials, out,
                                          16 * 16 * planes, 1.0 / (double)n);
}